// Round 2
// baseline (829.395 us; speedup 1.0000x reference)
//
#include <hip/hip_runtime.h>
#include <math.h>

// MoE gate: logits = X[T,4096] @ W^T[4096,64]; softmax over 64; top-2.
// Output layout (float32): [T*2] indices-as-float, then [T*2] weights.
//
// Tiling: 64 tokens x 64 experts per workgroup, BK=64.
// Staging: global_load_lds width 16 (async, no VGPR round-trip).
// LDS layout: row-major [64][64] floats, XOR-swizzled at float4 granularity
// with key = (row>>2) so compute-side ds_read_b128 has <=2-way bank conflicts
// (free per m136) while the staging store pattern stays base + lane*16
// (required by global_load_lds's wave-uniform-base semantics, m104/m108).
//
// R1 note: R0 bench died with "container failed twice" (infra). Kernel
// re-audited (swizzle algebra, barrier structure, OOB) — resubmitting
// unchanged for a first measurement.

#define BK 64

__device__ __forceinline__ void gl_lds16(const float* g, float* l) {
  __builtin_amdgcn_global_load_lds(
      (const __attribute__((address_space(1))) unsigned int*)g,
      (__attribute__((address_space(3))) unsigned int*)l,
      16, 0, 0);
}

__global__ __launch_bounds__(256)
void moe_gate(const float* __restrict__ X, const float* __restrict__ W,
              float* __restrict__ out, int T) {
  __shared__ float smem[8192];
  float* sx = smem;          // [64 tokens][64 k] swizzled
  float* sw = smem + 4096;   // [64 experts][64 k] swizzled

  const int t    = threadIdx.x;
  const int lane = t & 63;
  const int wave = t >> 6;
  const int tr   = t & 15;   // token-group  (4 tokens: tr*4+i)
  const int tc   = t >> 4;   // expert-group (4 experts: tc*4+j)
  const long tok0 = (long)blockIdx.x * 64;

  // --- staging pointers (advance by k0 in the loop) ---
  const float* xg[4];
  const float* wg[4];
  float* ldx[4];
  float* ldw[4];
  {
    const int rl = lane >> 4;       // 0..3 row-within-instruction
    const int c4 = lane & 15;       // float4 slot 0..15
    #pragma unroll
    for (int i = 0; i < 4; ++i) {
      const int r  = wave * 16 + i * 4 + rl;       // tile row 0..63
      const int sz = (wave * 4 + i) & 15;          // = r>>2 (lane-invariant)
      const int gc = c4 ^ sz;                      // swizzled global col4
      xg[i] = X + (tok0 + r) * 4096 + gc * 4;
      wg[i] = W + (long)r * 4096 + gc * 4;
      ldx[i] = sx + (wave * 16 + i * 4) * 64;      // wave-uniform LDS base
      ldw[i] = sw + (wave * 16 + i * 4) * 64;
    }
  }

  float acc[4][4];
  #pragma unroll
  for (int i = 0; i < 4; ++i)
    #pragma unroll
    for (int j = 0; j < 4; ++j) acc[i][j] = 0.f;

  for (int k0 = 0; k0 < 4096; k0 += BK) {
    #pragma unroll
    for (int i = 0; i < 4; ++i) {
      gl_lds16(xg[i] + k0, ldx[i]);
      gl_lds16(wg[i] + k0, ldw[i]);
    }
    __syncthreads();   // drains vmcnt (compiler emits waitcnt before barrier)

    // chunk-local accumulator: bounds fp32 rounding error (~1e-6 total)
    // so top-2 index decisions match the reference's accumulation.
    float cacc[4][4];
    #pragma unroll
    for (int i = 0; i < 4; ++i)
      #pragma unroll
      for (int j = 0; j < 4; ++j) cacc[i][j] = 0.f;

    #pragma unroll
    for (int k4 = 0; k4 < 16; ++k4) {
      float4 xa[4], wb[4];
      #pragma unroll
      for (int i = 0; i < 4; ++i) {
        const int row  = tr * 4 + i;
        const int slot = k4 ^ (row >> 2);
        xa[i] = *(const float4*)(sx + row * 64 + slot * 4);
      }
      #pragma unroll
      for (int j = 0; j < 4; ++j) {
        const int e    = tc * 4 + j;
        const int slot = k4 ^ (e >> 2);
        wb[j] = *(const float4*)(sw + e * 64 + slot * 4);
      }
      #pragma unroll
      for (int i = 0; i < 4; ++i)
        #pragma unroll
        for (int j = 0; j < 4; ++j) {
          cacc[i][j] = fmaf(xa[i].x, wb[j].x, cacc[i][j]);
          cacc[i][j] = fmaf(xa[i].y, wb[j].y, cacc[i][j]);
          cacc[i][j] = fmaf(xa[i].z, wb[j].z, cacc[i][j]);
          cacc[i][j] = fmaf(xa[i].w, wb[j].w, cacc[i][j]);
        }
    }
    #pragma unroll
    for (int i = 0; i < 4; ++i)
      #pragma unroll
      for (int j = 0; j < 4; ++j) acc[i][j] += cacc[i][j];
    __syncthreads();   // protect LDS before next chunk's staging
  }

  // --- epilogue: logits -> LDS [64][65], then 1 thread per token ---
  #pragma unroll
  for (int i = 0; i < 4; ++i)
    #pragma unroll
    for (int j = 0; j < 4; ++j)
      smem[(tr * 4 + i) * 65 + tc * 4 + j] = acc[i][j];
  __syncthreads();

  if (t < 64) {
    const float* row = smem + t * 65;
    // top-2 on logits; strict '>' = stable lowest-index-first on ties,
    // matching jax.lax.top_k. max logit == b1.
    float b1 = -1e30f, b2 = -1e30f;
    int i1 = 0, i2 = 0;
    for (int e = 0; e < 64; ++e) {
      const float v = row[e];
      if (v > b1)      { b2 = b1; i2 = i1; b1 = v; i1 = e; }
      else if (v > b2) { b2 = v; i2 = e; }
    }
    float s = 0.f;
    for (int e = 0; e < 64; ++e) s += expf(row[e] - b1);
    const float inv = 1.0f / s;
    const long gt = tok0 + t;
    out[gt * 2 + 0] = (float)i1;
    out[gt * 2 + 1] = (float)i2;
    float* ow = out + (long)T * 2;
    ow[gt * 2 + 0] = inv;                 // exp(b1-b1)/s
    ow[gt * 2 + 1] = expf(b2 - b1) * inv;
  }
}

extern "C" void kernel_launch(void* const* d_in, const int* in_sizes, int n_in,
                              void* d_out, int out_size, void* d_ws, size_t ws_size,
                              hipStream_t stream) {
  const float* X = (const float*)d_in[0];   // [4,8192,4096] fp32
  const float* W = (const float*)d_in[1];   // [64,4096] fp32
  float* out = (float*)d_out;               // [T*2] idx-as-float, [T*2] weights
  const int T = in_sizes[0] / 4096;         // 32768 tokens
  const int grid = T / 64;                  // 512 workgroups
  hipLaunchKernelGGL(moe_gate, dim3(grid), dim3(256), 0, stream, X, W, out, T);
}